// Round 6
// baseline (212.794 us; speedup 1.0000x reference)
//
#include <hip/hip_runtime.h>

constexpr int N_NODES = 50000;
constexpr int N_EDGES = 800000;
constexpr int NBINS   = 782;     // ceil(50000/64), 64 nodes per bin
constexpr int BINCAP  = 1536;    // mean 1024, sd 32 -> +16 sigma, never overflows
constexpr int FILL_BLOCKS = 261; // 261*3072 >= 800000
constexpr int TILE_BLOCKS = 782; // 64-node conversion tiles
constexpr int AUX_BLOCKS  = 192; // wt/g/out init
constexpr int PLANE   = 600000;  // ushorts per column-plane (50000 * 12, unpadded)

typedef __attribute__((ext_vector_type(8))) short short8;
typedef __attribute__((ext_vector_type(8))) unsigned short ushort8;
typedef __attribute__((ext_vector_type(4))) short short4v;
typedef __attribute__((ext_vector_type(4))) unsigned short ushort4v;
typedef __attribute__((ext_vector_type(4))) float floatx4;

static __device__ __forceinline__ unsigned short f2bf(float f) {
    unsigned u = __float_as_uint(f);
    u += 0x7FFF + ((u >> 16) & 1);
    return (unsigned short)(u >> 16);
}
static __device__ __forceinline__ float bf2f(unsigned short s) {
    return __uint_as_float(((unsigned)s) << 16);
}

// ---------------- K1: fused prep + edge binning.
// Blocks [0,261): edge binning (bin_cnt pre-zeroed by memset node).
// Blocks [261,1043): 64-node tiles: coalesced x read -> xb + 8 column planes
//   (R5's plane init read x at 384B stride — scattered; now via LDS tile).
// Blocks [1043,1235): wt transpose, zero g, out = b2-init for split-K mlp2.
__global__ __launch_bounds__(256) void k_prep_fill(const float* __restrict__ x,
                                                   unsigned short* __restrict__ xb,
                                                   unsigned short* __restrict__ xbp,
                                                   const float* __restrict__ Wrel,
                                                   const float* __restrict__ Wroot,
                                                   unsigned short* __restrict__ wt,
                                                   float* __restrict__ g,
                                                   const float* __restrict__ b2,
                                                   float* __restrict__ out,
                                                   const int* __restrict__ ei,
                                                   int* __restrict__ bin_cnt,
                                                   int* __restrict__ eb) {
    const int t = threadIdx.x;
    if (blockIdx.x < FILL_BLOCKS) {
        __shared__ int h[NBINS];
        __shared__ int gbase[NBINS];
        for (int b = t; b < NBINS; b += 256) h[b] = 0;
        __syncthreads();
        int e0 = blockIdx.x * 3072;
#pragma unroll
        for (int i = 0; i < 12; i++) {
            int e = e0 + i * 256 + t;
            if (e < N_EDGES) atomicAdd(&h[ei[N_EDGES + e] >> 6], 1);
        }
        __syncthreads();
        for (int b = t; b < NBINS; b += 256) {
            int c = h[b];
            gbase[b] = c ? atomicAdd(&bin_cnt[b], c) : 0;
            h[b] = 0;
        }
        __syncthreads();
#pragma unroll
        for (int i = 0; i < 12; i++) {
            int e = e0 + i * 256 + t;
            if (e < N_EDGES) {
                int s = ei[e];
                int d = ei[N_EDGES + e];
                int bin = d >> 6;
                int p = gbase[bin] + atomicAdd(&h[bin], 1);
                if (p < BINCAP)                   // hardening: never write OOB
                    eb[bin * BINCAP + p] = (s << 6) | (d & 63);
            }
        }
        return;
    }
    if (blockIdx.x < FILL_BLOCKS + TILE_BLOCKS) {
        // ---- 64-node conversion tile: x (fp32) -> xb (bf16) + 8 planes
        __shared__ unsigned short tile[64 * 96];    // 12 KB
        const int nb = (blockIdx.x - FILL_BLOCKS) * 64;   // node base
        const bool ok = (nb + (t >> 2)) < N_NODES;        // lane covers 1/4 node row
        ushort8 r[3];
        if (ok) {
            const float4* px = reinterpret_cast<const float4*>(x + (size_t)nb * 96 + t * 24);
#pragma unroll
            for (int i = 0; i < 3; i++) {
                float4 a = px[2 * i], c = px[2 * i + 1];
                r[i][0] = f2bf(a.x); r[i][1] = f2bf(a.y);
                r[i][2] = f2bf(a.z); r[i][3] = f2bf(a.w);
                r[i][4] = f2bf(c.x); r[i][5] = f2bf(c.y);
                r[i][6] = f2bf(c.z); r[i][7] = f2bf(c.w);
            }
            ushort8* dst = reinterpret_cast<ushort8*>(xb + (size_t)nb * 96 + t * 24);
            ushort8* lds = reinterpret_cast<ushort8*>(tile + t * 24);
#pragma unroll
            for (int i = 0; i < 3; i++) { dst[i] = r[i]; lds[i] = r[i]; }
        }
        __syncthreads();
        // plane writes: 512 (plane,node) pairs, 24 B each, coalesced
#pragma unroll
        for (int i = 0; i < 2; i++) {
            int pr = t + 256 * i;
            int p = pr >> 6, node = pr & 63;
            if (nb + node < N_NODES) {
                const unsigned short* src = tile + node * 96 + p * 12;
                unsigned short* dst = xbp + (size_t)p * PLANE + (size_t)(nb + node) * 12;
#pragma unroll
                for (int j = 0; j < 3; j++)
                    *reinterpret_cast<ushort4v*>(dst + j * 4) =
                        *reinterpret_cast<const ushort4v*>(src + j * 4);
            }
        }
        return;
    }
    // ---- aux init: wt transpose (49152), g zero, out = b2 broadcast
    int idx = (blockIdx.x - FILL_BLOCKS - TILE_BLOCKS) * 256 + t;   // [0,49152)
    {
        int k = idx % 192;
        int n = idx / 192;
        float v = (k < 96) ? Wrel[k * 256 + n] : Wroot[(k - 96) * 256 + n];
        wt[idx] = f2bf(v);
    }
    if (idx < 16384)
        reinterpret_cast<float4*>(g)[idx] = make_float4(0.f, 0.f, 0.f, 0.f);
    {
        int base = idx * 4;                 // [0, 196608)
        int rr = base % 768;                // multiple of 4, <= 764
        float4 bv = *reinterpret_cast<const float4*>(b2 + rr);
        *reinterpret_cast<float4*>(out + base) = bv;
    }
}

// ---------------- K2: per-bin counting sort, ONCE (R5 ran it 8x, once per
// cg block -> 6.4M redundant LDS atomics + 1.9M bank conflicts = 44us).
// Writes globally sorted src list ebs + packed (base<<16|deg) per node.
__global__ __launch_bounds__(256) void k_sort(const int* __restrict__ bin_cnt,
                                              const int* __restrict__ eb,
                                              int* __restrict__ ebs,
                                              int* __restrict__ ndb) {
    __shared__ int h[64], base[64], cursor[64];
    const int b = blockIdx.x, t = threadIdx.x;
    const int total = min(bin_cnt[b], BINCAP);
    const int* ebb = eb + b * BINCAP;
    if (t < 64) h[t] = 0;
    __syncthreads();
    for (int i = t; i < total; i += 256) atomicAdd(&h[ebb[i] & 63], 1);
    __syncthreads();
    if (t < 64) {
        int v = h[t], s = v;
#pragma unroll
        for (int dd = 1; dd < 64; dd <<= 1) {
            int o = __shfl_up(s, dd);
            if (t >= dd) s += o;
        }
        base[t] = s - v;
        cursor[t] = s - v;
        ndb[b * 64 + t] = ((s - v) << 16) | v;
    }
    __syncthreads();
    for (int i = t; i < total; i += 256) {
        int m = ebb[i];
        int p = atomicAdd(&cursor[m & 63], 1);
        ebs[b * BINCAP + p] = m >> 6;
    }
}

// ---------------- K3: XCD-local pure gather. Block (bin, cg=bid&7); the
// measured round-robin bid%8->XCD mapping makes each XCD read only its own
// 1.2 MB plane (L2-resident; R4/R5 confirmed FETCH 18-19 MB vs 63 random).
// 192 thr = 64 nodes x 3 col-quads; zero LDS; register accumulation.
__global__ __launch_bounds__(192) void k_agg(const int* __restrict__ ndb,
                                             const int* __restrict__ ebs,
                                             const unsigned short* __restrict__ xbp,
                                             unsigned short* __restrict__ agg) {
    const int bid = blockIdx.x;
    const int bin = bid >> 3, cg = bid & 7;
    const int t = threadIdx.x;
    const int node = t / 3;
    const int q = t - node * 3;
    const unsigned short* xp = xbp + (size_t)cg * PLANE + q * 4;
    const int nd  = ndb[bin * 64 + node];
    const int deg = nd & 0xffff;
    const int* lst = ebs + bin * BINCAP + (nd >> 16);
    float acc[4] = {0.f, 0.f, 0.f, 0.f};
    int e = 0;
    for (; e + 4 <= deg; e += 4) {
        int s0 = lst[e], s1 = lst[e + 1], s2 = lst[e + 2], s3 = lst[e + 3];
        ushort4v v0 = *reinterpret_cast<const ushort4v*>(xp + s0 * 12);
        ushort4v v1 = *reinterpret_cast<const ushort4v*>(xp + s1 * 12);
        ushort4v v2 = *reinterpret_cast<const ushort4v*>(xp + s2 * 12);
        ushort4v v3 = *reinterpret_cast<const ushort4v*>(xp + s3 * 12);
#pragma unroll
        for (int j = 0; j < 4; j++)
            acc[j] += (bf2f(v0[j]) + bf2f(v1[j])) + (bf2f(v2[j]) + bf2f(v3[j]));
    }
    for (; e < deg; e++) {
        int s0 = lst[e];
        ushort4v v0 = *reinterpret_cast<const ushort4v*>(xp + s0 * 12);
#pragma unroll
        for (int j = 0; j < 4; j++) acc[j] += bf2f(v0[j]);
    }
    ushort4v r;
#pragma unroll
    for (int j = 0; j < 4; j++) r[j] = f2bf(acc[j]);
    *reinterpret_cast<ushort4v*>(
        agg + (size_t)(bin * 64 + node) * 96 + cg * 12 + q * 4) = r;
}

// ---------------- K4: GEMM 64x256x192 + bias/relu/segment-max pool.
// One 256-thr block per bin (4 waves x 64-col slice); A-operand rows
// stream from agg (cols 0..95) and xb (cols 96..191). Unchanged.
__global__ __launch_bounds__(256, 4) void k_gemm(const unsigned short* __restrict__ agg,
                                                 const unsigned short* __restrict__ xb,
                                                 const unsigned short* __restrict__ wt,
                                                 const float* __restrict__ b_rel,
                                                 const int* __restrict__ batch,
                                                 int* __restrict__ g_i) {
    const int b = blockIdx.x, t = threadIdx.x;
    const int lane = t & 63;
    const int wave = t >> 6;
    const int quad = lane >> 4;
    const int l15  = lane & 15;
    const int row_base = b * 64;
    const int n0 = wave * 64;

    floatx4 C[4][4];
#pragma unroll
    for (int i = 0; i < 4; i++)
#pragma unroll
        for (int j = 0; j < 4; j++) C[i][j] = (floatx4)0.0f;

#pragma unroll
    for (int kc = 0; kc < 6; kc++) {
        short8 a4[4];
#pragma unroll
        for (int mf = 0; mf < 4; mf++) {
            if (kc < 3) {
                a4[mf] = *reinterpret_cast<const short8*>(
                    agg + (row_base + mf * 16 + l15) * 96 + kc * 32 + quad * 8);
            } else {
                int r = row_base + mf * 16 + l15;
                a4[mf] = (r < N_NODES)
                    ? *reinterpret_cast<const short8*>(xb + r * 96 + (kc - 3) * 32 + quad * 8)
                    : (short8)0;
            }
        }
        short8 b4[4];
#pragma unroll
        for (int nf = 0; nf < 4; nf++)
            b4[nf] = *reinterpret_cast<const short8*>(
                wt + (n0 + nf * 16 + l15) * 192 + kc * 32 + quad * 8);
#pragma unroll
        for (int mf = 0; mf < 4; mf++)
#pragma unroll
            for (int nf = 0; nf < 4; nf++)
                C[mf][nf] = __builtin_amdgcn_mfma_f32_16x16x32_bf16(
                    a4[mf], b4[nf], C[mf][nf], 0, 0, 0);
    }

    // ---- bias + relu + segment-max pool
    bool fast = (row_base + 63 < N_NODES) && (batch[row_base] == batch[row_base + 63]);
    if (fast) {
        int gid = batch[row_base];
#pragma unroll
        for (int nf = 0; nf < 4; nf++) {
            float m = C[0][nf][0];
#pragma unroll
            for (int mf = 0; mf < 4; mf++)
#pragma unroll
                for (int r = 0; r < 4; r++) m = fmaxf(m, C[mf][nf][r]);
            m = fmaxf(m, __shfl_xor(m, 16));
            m = fmaxf(m, __shfl_xor(m, 32));
            if (quad == 0) {
                int n = n0 + nf * 16 + l15;
                float v = fmaxf(m + b_rel[n], 0.0f);
                atomicMax(&g_i[gid * 256 + n], __float_as_int(v));
            }
        }
    } else {
#pragma unroll
        for (int mf = 0; mf < 4; mf++) {
            int rb = row_base + mf * 16 + quad * 4;
            if (rb >= N_NODES) continue;
            bool merged = (rb + 3 < N_NODES) && (batch[rb] == batch[rb + 3]);
            if (merged) {
                int gid = batch[rb];
#pragma unroll
                for (int nf = 0; nf < 4; nf++) {
                    float m = fmaxf(fmaxf(C[mf][nf][0], C[mf][nf][1]),
                                    fmaxf(C[mf][nf][2], C[mf][nf][3]));
                    int n = n0 + nf * 16 + l15;
                    float v = fmaxf(m + b_rel[n], 0.0f);
                    atomicMax(&g_i[gid * 256 + n], __float_as_int(v));
                }
            } else {
                for (int r = 0; r < 4; r++) {
                    int rg = rb + r;
                    if (rg >= N_NODES) break;
                    int gid = batch[rg];
#pragma unroll
                    for (int nf = 0; nf < 4; nf++) {
                        int n = n0 + nf * 16 + l15;
                        float v = fmaxf(C[mf][nf][r] + b_rel[n], 0.0f);
                        atomicMax(&g_i[gid * 256 + n], __float_as_int(v));
                    }
                }
            }
        }
    }
}

// ---------------- K5: g2 = relu(g @ W1 + b1). Round-2 version (proven):
// 512 blocks = 2048 waves; parallelism is the lever, not reuse.
__global__ __launch_bounds__(256) void k_mlp1(const float* __restrict__ g,
                                              const float* __restrict__ W1,
                                              const float* __restrict__ b1,
                                              float* __restrict__ g2) {
    __shared__ float sg[256];
    int m = blockIdx.x;
    int n = blockIdx.y * 256 + threadIdx.x;
    int t = threadIdx.x;
    sg[t] = g[m * 256 + t];
    __syncthreads();
    float a0 = 0.f, a1 = 0.f;
#pragma unroll 4
    for (int k = 0; k < 128; k++) {
        a0 += sg[k]       * W1[k * 512 + n];
        a1 += sg[k + 128] * W1[(k + 128) * 512 + n];
    }
    g2[m * 512 + n] = fmaxf(a0 + a1 + b1[n], 0.f);
}

// ---------------- K6: out += g2 @ W2 (split-K x4, out pre-init'd with b2).
// Round-2 version (proven). NO grid.sync — cooperative sync cost ~100us (R3).
__global__ __launch_bounds__(256) void k_mlp2(const float* __restrict__ g2,
                                              const float* __restrict__ W2,
                                              float* __restrict__ out) {
    __shared__ float sg[4 * 128];
    int m0 = blockIdx.x * 4;
    int n  = blockIdx.y * 256 + threadIdx.x;
    int k0 = blockIdx.z * 128;
    int t  = threadIdx.x;
#pragma unroll
    for (int j = t; j < 512; j += 256)
        sg[j] = g2[(m0 + (j >> 7)) * 512 + k0 + (j & 127)];
    __syncthreads();
    float a[4];
#pragma unroll
    for (int i = 0; i < 4; i++) a[i] = 0.f;
#pragma unroll 4
    for (int k = 0; k < 128; k++) {
        float w = W2[(k0 + k) * 768 + n];
#pragma unroll
        for (int i = 0; i < 4; i++) a[i] += sg[i * 128 + k] * w;
    }
#pragma unroll
    for (int i = 0; i < 4; i++)
        atomicAdd(&out[(m0 + i) * 768 + n], a[i]);
}

extern "C" void kernel_launch(void* const* d_in, const int* in_sizes, int n_in,
                              void* d_out, int out_size, void* d_ws, size_t ws_size,
                              hipStream_t stream) {
    const float* x      = (const float*)d_in[0];
    const int*   ei     = (const int*)d_in[1];
    const int*   batch  = (const int*)d_in[2];
    const float* W_rel  = (const float*)d_in[3];
    const float* b_rel  = (const float*)d_in[4];
    const float* W_root = (const float*)d_in[5];
    const float* W1     = (const float*)d_in[6];
    const float* b1     = (const float*)d_in[7];
    const float* W2     = (const float*)d_in[8];
    const float* b2     = (const float*)d_in[9];
    float* out = (float*)d_out;

    char* ws = (char*)d_ws;
    unsigned short* xb  = (unsigned short*)(ws);             //  9,600,000
    unsigned short* xbp = (unsigned short*)(ws + 9600000);   //  9,600,000 (8 planes)
    float* g       = (float*)(ws + 19200000);                //    262,144
    int* bin_cnt   = (int*)  (ws + 19462144);                //      3,136 (784 ints)
    int* eb        = (int*)  (ws + 19465280);                //  4,804,608 (782*1536*4)
    int* ebs       = (int*)  (ws + 24269888);                //  4,804,608 (sorted src)
    int* ndb       = (int*)  (ws + 29074496);                //    200,192 (50048 packed)
    unsigned short* agg = (unsigned short*)(ws + 29274688);  //  9,609,216 (782*64*96*2)
    float* g2      = (float*)(ws + 38883904);                //    524,288
    unsigned short* wt = (unsigned short*)(ws + 39408192);   //     98,304
    // total ~39.5 MB

    hipMemsetAsync(bin_cnt, 0, 784 * sizeof(int), stream);
    k_prep_fill<<<FILL_BLOCKS + TILE_BLOCKS + AUX_BLOCKS, 256, 0, stream>>>(
        x, xb, xbp, W_rel, W_root, wt, g, b2, out, ei, bin_cnt, eb);
    k_sort<<<NBINS, 256, 0, stream>>>(bin_cnt, eb, ebs, ndb);
    k_agg<<<NBINS * 8, 192, 0, stream>>>(ndb, ebs, xbp, agg);
    k_gemm<<<NBINS, 256, 0, stream>>>(agg, xb, wt, b_rel, batch, (int*)g);
    k_mlp1<<<dim3(256, 2), 256, 0, stream>>>(g, W1, b1, g2);
    k_mlp2<<<dim3(64, 3, 4), 256, 0, stream>>>(g2, W2, out);
}

// Round 7
// 179.098 us; speedup vs baseline: 1.1881x; 1.1881x over previous
//
#include <hip/hip_runtime.h>

constexpr int N_NODES = 50000;
constexpr int N_EDGES = 800000;
constexpr int NBINS   = 782;     // ceil(50000/64), 64 nodes per bin
constexpr int BINCAP  = 1536;    // mean 1024, sd 32 -> +16 sigma, never overflows
constexpr int FILL_BLOCKS = 261; // 261*3072 >= 800000

typedef __attribute__((ext_vector_type(8))) short short8;
typedef __attribute__((ext_vector_type(8))) unsigned short ushort8;
typedef __attribute__((ext_vector_type(4))) short short4v;
typedef __attribute__((ext_vector_type(4))) unsigned short ushort4v;
typedef __attribute__((ext_vector_type(4))) float floatx4;

static __device__ __forceinline__ unsigned short f2bf(float f) {
    unsigned u = __float_as_uint(f);
    u += 0x7FFF + ((u >> 16) & 1);
    return (unsigned short)(u >> 16);
}
static __device__ __forceinline__ float bf2f(unsigned short s) {
    return __uint_as_float(((unsigned)s) << 16);
}

// ---------------- K1: fused prep + edge binning (R2 prep + R3/R6 fusion).
// Blocks [0,261): edge binning (bin_cnt pre-zeroed by the memset node).
// Blocks [261,2605): x fp32->bf16 (coalesced streaming), wt transpose,
//   zero g, out = b2-init for split-K mlp2. Disjoint data -> legal overlap;
//   binning runs concurrently with conversion instead of as its own launch.
__global__ __launch_bounds__(256) void k_prep_fill(const float* __restrict__ x,
                                                   unsigned short* __restrict__ xb,
                                                   const float* __restrict__ Wrel,
                                                   const float* __restrict__ Wroot,
                                                   unsigned short* __restrict__ wt,
                                                   float* __restrict__ g,
                                                   const float* __restrict__ b2,
                                                   float* __restrict__ out,
                                                   const int* __restrict__ ei,
                                                   int* __restrict__ bin_cnt,
                                                   int* __restrict__ eb) {
    const int t = threadIdx.x;
    if (blockIdx.x < FILL_BLOCKS) {
        __shared__ int h[NBINS];
        __shared__ int gbase[NBINS];
        for (int b = t; b < NBINS; b += 256) h[b] = 0;
        __syncthreads();
        int e0 = blockIdx.x * 3072;
#pragma unroll
        for (int i = 0; i < 12; i++) {
            int e = e0 + i * 256 + t;
            if (e < N_EDGES) atomicAdd(&h[ei[N_EDGES + e] >> 6], 1);
        }
        __syncthreads();
        for (int b = t; b < NBINS; b += 256) {
            int c = h[b];
            gbase[b] = c ? atomicAdd(&bin_cnt[b], c) : 0;
            h[b] = 0;
        }
        __syncthreads();
#pragma unroll
        for (int i = 0; i < 12; i++) {
            int e = e0 + i * 256 + t;
            if (e < N_EDGES) {
                int s = ei[e];
                int d = ei[N_EDGES + e];
                int bin = d >> 6;
                int p = gbase[bin] + atomicAdd(&h[bin], 1);
                if (p < BINCAP)                   // hardening: never write OOB
                    eb[bin * BINCAP + p] = (s << 6) | (d & 63);
            }
        }
        return;
    }
    // ---- prep part (R2 verbatim)
    int idx = (blockIdx.x - FILL_BLOCKS) * 256 + t;
    if (idx < 49152) {                                  // Wt[n][k] = bf16(Wcat[k][n])
        int k = idx % 192;
        int n = idx / 192;
        float v = (k < 96) ? Wrel[k * 256 + n] : Wroot[(k - 96) * 256 + n];
        wt[idx] = f2bf(v);
    }
    if (idx < 16384) {
        reinterpret_cast<float4*>(g)[idx] = make_float4(0.f, 0.f, 0.f, 0.f);
    }
    if (idx < 256 * 768) out[idx] = b2[idx % 768];      // bias-init for split-K mlp2
    if (idx >= N_NODES * 96 / 8) return;
    const float4* p = reinterpret_cast<const float4*>(x) + idx * 2;
    float4 u = p[0], v = p[1];
    short8 a;
    a[0] = (short)f2bf(u.x); a[1] = (short)f2bf(u.y);
    a[2] = (short)f2bf(u.z); a[3] = (short)f2bf(u.w);
    a[4] = (short)f2bf(v.x); a[5] = (short)f2bf(v.y);
    a[6] = (short)f2bf(v.z); a[7] = (short)f2bf(v.w);
    reinterpret_cast<short8*>(xb)[idx] = a;
}

// ---------------- fused gather + GEMM + pool. One block (512 thr) per bin.
// AT ROOFLINE (R2-measured): FETCH 63 MB = 43k unique src rows x 192 B x
// 8 XCDs (cross-XCD L2 replication, irreducible for a random graph); fill
// rate 1.21 TB/s = 64 B/cy/XCD L2-fill ceiling; doubling occupancy (R2) and
// XCD-local planes (R4-R6) both failed to beat it. Byte-identical to R2.
__global__ __launch_bounds__(512, 6) void k_gnn(const int* __restrict__ bin_cnt,
                                                const int* __restrict__ eb,
                                                const unsigned short* __restrict__ xb,
                                                const unsigned short* __restrict__ wt,
                                                const float* __restrict__ b_rel,
                                                const int* __restrict__ batch,
                                                int* __restrict__ g_i) {
    __shared__ int h[64], base[64], cursor[64];
    __shared__ int list[BINCAP];
    __shared__ unsigned short at[64 * 104];   // agg tile, padded row stride
    const int b = blockIdx.x, t = threadIdx.x;
    const int total = min(bin_cnt[b], BINCAP); // hardening: never read/sort OOB
    const int* ebb = eb + b * BINCAP;

    // ---- phase 1: counting sort by local node
    if (t < 64) h[t] = 0;
    __syncthreads();
    for (int i = t; i < total; i += 512) atomicAdd(&h[ebb[i] & 63], 1);
    __syncthreads();
    if (t < 64) {
        int v = h[t], s = v;
#pragma unroll
        for (int dd = 1; dd < 64; dd <<= 1) {
            int o = __shfl_up(s, dd);
            if (t >= dd) s += o;
        }
        base[t] = s - v;
        cursor[t] = s - v;
    }
    __syncthreads();
    for (int i = t; i < total; i += 512) {
        int m = ebb[i];
        int p = atomicAdd(&cursor[m & 63], 1);
        list[p] = m >> 6;
    }
    __syncthreads();

    // ---- phase 2: gather (thread = node x colgroup of 12), x4 unrolled
    // 8 threads/node: each handles cols [8cg,8cg+8) + [64+4cg,64+4cg+4)
    {
        int node = t >> 3, cg = t & 7;
        float acc[12];
#pragma unroll
        for (int j = 0; j < 12; j++) acc[j] = 0.f;
        int deg = h[node], lb = base[node];
        int e = 0;
        for (; e + 4 <= deg; e += 4) {
            int s0 = list[lb + e],     s1 = list[lb + e + 1];
            int s2 = list[lb + e + 2], s3 = list[lb + e + 3];
            ushort8 a0 = *reinterpret_cast<const ushort8*>(xb + s0 * 96 + cg * 8);
            ushort8 a1 = *reinterpret_cast<const ushort8*>(xb + s1 * 96 + cg * 8);
            ushort8 a2 = *reinterpret_cast<const ushort8*>(xb + s2 * 96 + cg * 8);
            ushort8 a3 = *reinterpret_cast<const ushort8*>(xb + s3 * 96 + cg * 8);
            ushort4v b0 = *reinterpret_cast<const ushort4v*>(xb + s0 * 96 + 64 + cg * 4);
            ushort4v b1 = *reinterpret_cast<const ushort4v*>(xb + s1 * 96 + 64 + cg * 4);
            ushort4v b2 = *reinterpret_cast<const ushort4v*>(xb + s2 * 96 + 64 + cg * 4);
            ushort4v b3 = *reinterpret_cast<const ushort4v*>(xb + s3 * 96 + 64 + cg * 4);
#pragma unroll
            for (int j = 0; j < 8; j++)
                acc[j] += (bf2f(a0[j]) + bf2f(a1[j])) + (bf2f(a2[j]) + bf2f(a3[j]));
#pragma unroll
            for (int j = 0; j < 4; j++)
                acc[8 + j] += (bf2f(b0[j]) + bf2f(b1[j])) + (bf2f(b2[j]) + bf2f(b3[j]));
        }
        for (; e < deg; e++) {
            int s0 = list[lb + e];
            ushort8 a0 = *reinterpret_cast<const ushort8*>(xb + s0 * 96 + cg * 8);
            ushort4v b0 = *reinterpret_cast<const ushort4v*>(xb + s0 * 96 + 64 + cg * 4);
#pragma unroll
            for (int j = 0; j < 8; j++) acc[j] += bf2f(a0[j]);
#pragma unroll
            for (int j = 0; j < 4; j++) acc[8 + j] += bf2f(b0[j]);
        }
        short8 r0;
        short4v r1;
#pragma unroll
        for (int j = 0; j < 8; j++) r0[j] = (short)f2bf(acc[j]);
#pragma unroll
        for (int j = 0; j < 4; j++) r1[j] = (short)f2bf(acc[8 + j]);
        *reinterpret_cast<short8*>(at + node * 104 + cg * 8) = r0;
        *reinterpret_cast<short4v*>(at + node * 104 + 64 + cg * 4) = r1;
    }
    __syncthreads();

    // ---- phase 3: GEMM 64x256x192 (wave = 32-col slice, 8 waves)
    const int lane = t & 63;
    const int wave = t >> 6;
    const int quad = lane >> 4;
    const int l15  = lane & 15;
    const int row_base = b * 64;
    const int n0 = wave * 32;

    floatx4 C[4][2];
#pragma unroll
    for (int i = 0; i < 4; i++)
#pragma unroll
        for (int j = 0; j < 2; j++) C[i][j] = (floatx4)0.0f;

#pragma unroll
    for (int kc = 0; kc < 6; kc++) {
        short8 a4[4];
#pragma unroll
        for (int mf = 0; mf < 4; mf++) {
            if (kc < 3) {
                a4[mf] = *reinterpret_cast<const short8*>(
                    at + (mf * 16 + l15) * 104 + kc * 32 + quad * 8);
            } else {
                int r = row_base + mf * 16 + l15;
                a4[mf] = (r < N_NODES)
                    ? *reinterpret_cast<const short8*>(xb + r * 96 + (kc - 3) * 32 + quad * 8)
                    : (short8)0;
            }
        }
        short8 b4[2];
#pragma unroll
        for (int nf = 0; nf < 2; nf++)
            b4[nf] = *reinterpret_cast<const short8*>(
                wt + (n0 + nf * 16 + l15) * 192 + kc * 32 + quad * 8);
#pragma unroll
        for (int mf = 0; mf < 4; mf++)
#pragma unroll
            for (int nf = 0; nf < 2; nf++)
                C[mf][nf] = __builtin_amdgcn_mfma_f32_16x16x32_bf16(
                    a4[mf], b4[nf], C[mf][nf], 0, 0, 0);
    }

    // ---- phase 4: bias + relu + segment-max pool
    bool fast = (row_base + 63 < N_NODES) && (batch[row_base] == batch[row_base + 63]);
    if (fast) {
        int gid = batch[row_base];
#pragma unroll
        for (int nf = 0; nf < 2; nf++) {
            float m = C[0][nf][0];
#pragma unroll
            for (int mf = 0; mf < 4; mf++)
#pragma unroll
                for (int r = 0; r < 4; r++) m = fmaxf(m, C[mf][nf][r]);
            m = fmaxf(m, __shfl_xor(m, 16));
            m = fmaxf(m, __shfl_xor(m, 32));
            if (quad == 0) {
                int n = n0 + nf * 16 + l15;
                float v = fmaxf(m + b_rel[n], 0.0f);
                atomicMax(&g_i[gid * 256 + n], __float_as_int(v));
            }
        }
    } else {
#pragma unroll
        for (int mf = 0; mf < 4; mf++) {
            int rb = row_base + mf * 16 + quad * 4;
            if (rb >= N_NODES) continue;
            bool merged = (rb + 3 < N_NODES) && (batch[rb] == batch[rb + 3]);
            if (merged) {
                int gid = batch[rb];
#pragma unroll
                for (int nf = 0; nf < 2; nf++) {
                    float m = fmaxf(fmaxf(C[mf][nf][0], C[mf][nf][1]),
                                    fmaxf(C[mf][nf][2], C[mf][nf][3]));
                    int n = n0 + nf * 16 + l15;
                    float v = fmaxf(m + b_rel[n], 0.0f);
                    atomicMax(&g_i[gid * 256 + n], __float_as_int(v));
                }
            } else {
                for (int r = 0; r < 4; r++) {
                    int rg = rb + r;
                    if (rg >= N_NODES) break;
                    int gid = batch[rg];
#pragma unroll
                    for (int nf = 0; nf < 2; nf++) {
                        int n = n0 + nf * 16 + l15;
                        float v = fmaxf(C[mf][nf][r] + b_rel[n], 0.0f);
                        atomicMax(&g_i[gid * 256 + n], __float_as_int(v));
                    }
                }
            }
        }
    }
}

// ---------------- K4: g2 = relu(g @ W1 + b1). R2 version (proven):
// 512 blocks = 2048 waves; parallelism is the lever, not reuse.
__global__ __launch_bounds__(256) void k_mlp1(const float* __restrict__ g,
                                              const float* __restrict__ W1,
                                              const float* __restrict__ b1,
                                              float* __restrict__ g2) {
    __shared__ float sg[256];
    int m = blockIdx.x;
    int n = blockIdx.y * 256 + threadIdx.x;
    int t = threadIdx.x;
    sg[t] = g[m * 256 + t];
    __syncthreads();
    float a0 = 0.f, a1 = 0.f;
#pragma unroll 4
    for (int k = 0; k < 128; k++) {
        a0 += sg[k]       * W1[k * 512 + n];
        a1 += sg[k + 128] * W1[(k + 128) * 512 + n];
    }
    g2[m * 512 + n] = fmaxf(a0 + a1 + b1[n], 0.f);
}

// ---------------- K5: out += g2 @ W2 (split-K x4, out pre-init'd with b2).
// R2 version (proven). NO grid.sync — cooperative sync cost ~100us (R3).
__global__ __launch_bounds__(256) void k_mlp2(const float* __restrict__ g2,
                                              const float* __restrict__ W2,
                                              float* __restrict__ out) {
    __shared__ float sg[4 * 128];
    int m0 = blockIdx.x * 4;
    int n  = blockIdx.y * 256 + threadIdx.x;
    int k0 = blockIdx.z * 128;
    int t  = threadIdx.x;
#pragma unroll
    for (int j = t; j < 512; j += 256)
        sg[j] = g2[(m0 + (j >> 7)) * 512 + k0 + (j & 127)];
    __syncthreads();
    float a[4];
#pragma unroll
    for (int i = 0; i < 4; i++) a[i] = 0.f;
#pragma unroll 4
    for (int k = 0; k < 128; k++) {
        float w = W2[(k0 + k) * 768 + n];
#pragma unroll
        for (int i = 0; i < 4; i++) a[i] += sg[i * 128 + k] * w;
    }
#pragma unroll
    for (int i = 0; i < 4; i++)
        atomicAdd(&out[(m0 + i) * 768 + n], a[i]);
}

extern "C" void kernel_launch(void* const* d_in, const int* in_sizes, int n_in,
                              void* d_out, int out_size, void* d_ws, size_t ws_size,
                              hipStream_t stream) {
    const float* x      = (const float*)d_in[0];
    const int*   ei     = (const int*)d_in[1];
    const int*   batch  = (const int*)d_in[2];
    const float* W_rel  = (const float*)d_in[3];
    const float* b_rel  = (const float*)d_in[4];
    const float* W_root = (const float*)d_in[5];
    const float* W1     = (const float*)d_in[6];
    const float* b1     = (const float*)d_in[7];
    const float* W2     = (const float*)d_in[8];
    const float* b2     = (const float*)d_in[9];
    float* out = (float*)d_out;

    char* ws = (char*)d_ws;
    unsigned short* xb = (unsigned short*)(ws);              //  9,600,000
    float* g       = (float*)(ws + 9600000);                 //    262,144
    int* bin_cnt   = (int*)  (ws + 9862144);                 //      3,136 (784 ints)
    int* eb        = (int*)  (ws + 9865280);                 //  4,804,608 (782*1536*4)
    float* g2      = (float*)(ws + 14669888);                //    524,288
    unsigned short* wt = (unsigned short*)(ws + 15194176);   //     98,304

    hipMemsetAsync(bin_cnt, 0, 784 * sizeof(int), stream);
    k_prep_fill<<<FILL_BLOCKS + 2344, 256, 0, stream>>>(x, xb, W_rel, W_root, wt,
                                                        g, b2, out, ei, bin_cnt, eb);
    k_gnn<<<NBINS, 512, 0, stream>>>(bin_cnt, eb, xb, wt, b_rel, batch, (int*)g);
    k_mlp1<<<dim3(256, 2), 256, 0, stream>>>(g, W1, b1, g2);
    k_mlp2<<<dim3(64, 3, 4), 256, 0, stream>>>(g2, W2, out);
}